// Round 10
// baseline (432.471 us; speedup 1.0000x reference)
//
#include <hip/hip_runtime.h>
#include <math.h>

typedef __attribute__((ext_vector_type(4)))  int   i32x4;
typedef __attribute__((ext_vector_type(16))) int   i32x16;
typedef __attribute__((ext_vector_type(4)))  float f32x4;

namespace {
constexpr int IN_F   = 4096;
constexpr int OUT_F  = 4096;
constexpr int TOKENS = 8192;
constexpr int PACKED = IN_F / 16;      // 256 words per weight row

// fast-path gemm: 256x256 block, 8 waves (2M x 4N), wave tile 128x64,
// BK=64, A+B LDS triple-buffer (96 KB), counted vmcnt(4) - never drains.
constexpr int BM   = 256;
constexpr int BN   = 256;
constexpr int BK   = 64;               // 4 chunks of 16 k
constexpr int NTHR = 512;
constexpr int NT   = IN_F / BK;        // 64 K-tiles

constexpr size_t XQ_BYTES = (size_t)TOKENS * IN_F;        // 33.55 MB
constexpr size_t XS_BYTES = (size_t)TOKENS * 4;           // 32 KB
constexpr size_t BQ_OFF   = XQ_BYTES + XS_BYTES;
constexpr size_t BQ_BYTES = (size_t)PACKED * OUT_F * 16;  // 16.78 MB
constexpr size_t WS_NEED  = BQ_OFF + BQ_BYTES;            // ~50.4 MB
}

// 16x 2-bit {0,1,2}  ->  16x i8 {-1,0,1}  (4 dwords)
__device__ __forceinline__ i32x4 unpack16(unsigned w) {
  i32x4 r;
#pragma unroll
  for (int g = 0; g < 4; ++g) {
    unsigned t = (w >> (8 * g)) & 0xFFu;
    unsigned s = (t | (t << 6) | (t << 12) | (t << 18)) & 0x03030303u;
    r[g] = (int)((((s | 0x80808080u) - 0x01010101u) ^ 0x80808080u));
  }
  return r;
}

// ------- pass 1 (fused): rowquant (blocks 0..2047) + unpackB (rest) -------
__global__ __launch_bounds__(256)
void prep(const float* __restrict__ X, signed char* __restrict__ XQ,
          float* __restrict__ XS, const unsigned* __restrict__ PW,
          signed char* __restrict__ BQ) {
  if (blockIdx.x < TOKENS / 4) {
    const int row  = blockIdx.x * 4 + (threadIdx.x >> 6);
    const int lane = threadIdx.x & 63;
    const float* xr = X + (size_t)row * IN_F;

    f32x4 v[16];
    float m = 0.f;
#pragma unroll
    for (int c = 0; c < 16; ++c) {
      v[c] = *(const f32x4*)(xr + c * 256 + lane * 4);
      m = fmaxf(m, fmaxf(fmaxf(fabsf(v[c].x), fabsf(v[c].y)),
                         fmaxf(fabsf(v[c].z), fabsf(v[c].w))));
    }
#pragma unroll
    for (int off = 32; off; off >>= 1) m = fmaxf(m, __shfl_xor(m, off, 64));
    m = fmaxf(m, 1e-5f);
    const float r = 127.f / m;

#pragma unroll
    for (int c = 0; c < 16; ++c) {
      int q0 = (int)rintf(v[c].x * r);
      int q1 = (int)rintf(v[c].y * r);
      int q2 = (int)rintf(v[c].z * r);
      int q3 = (int)rintf(v[c].w * r);
      unsigned d = (q0 & 255) | ((q1 & 255) << 8) | ((q2 & 255) << 16) | ((q3 & 255) << 24);
      *(unsigned*)(XQ + (size_t)row * IN_F + c * 256 + lane * 4) = d;
    }
    if (lane == 0) XS[row] = m;
  } else {
    // BQ layout: [c (k/16)][n][16 bytes]
    const int g = (blockIdx.x - TOKENS / 4) * 256 + threadIdx.x;  // 1M words
    const int c = g >> 12;                                         // 0..255
    const int n = g & 4095;
    i32x4 u = unpack16(PW[(size_t)n * PACKED + c]);
    *(i32x4*)(BQ + ((size_t)c * OUT_F + n) * 16) = u;
  }
}

// ------------- pass 2 (fast): triple-buffer never-drain i8 GEMM ------------
// Per thread per tile: 2 A-stage + 2 B-stage global_load_lds = 4 vmem insts.
// Steady state entering tile kt: 4 outstanding (kt+1's). Issue kt+2's 4 -> 8,
// compute kt, then vmcnt(4): drains exactly kt+1's, keeps kt+2's in flight.
// Loads get ~2 tiles of latency cover; the wait is counted, NEVER 0 mid-loop.
// WAR: stage(kt+2) overwrites buffer last read by compute(kt-1), which all
// waves finished before the barrier ending tile kt-1. (3 buffers rotate.)

#define STAGE_A(BUFO_, KT_)                                                     \
  {                                                                             \
    _Pragma("unroll")                                                           \
    for (int j = 0; j < 2; ++j) {                                               \
      const int idx  = tid + j * 512;           /* c = idx>>8, row = idx&255 */ \
      const signed char* src =                                                  \
          XQ + (size_t)(m0 + (idx & 255)) * IN_F + (KT_) * BK + (idx >> 8) * 16;\
      signed char* dst = lA + (BUFO_) + (w * 64 + j * 512) * 16;                \
      __builtin_amdgcn_global_load_lds(                                         \
          (const __attribute__((address_space(1))) void*)src,                   \
          (__attribute__((address_space(3))) void*)dst, 16, 0, 0);              \
    }                                                                           \
  }

#define STAGE_B(BUFO_, KT_)                                                     \
  {                                                                             \
    _Pragma("unroll")                                                           \
    for (int j = 0; j < 2; ++j) {                                               \
      const int idx  = tid + j * 512;                                           \
      const signed char* src = BQ +                                             \
          ((size_t)((KT_) * 4 + (idx >> 8)) * OUT_F + n0 + (idx & 255)) * 16;   \
      signed char* dst = lB + (BUFO_) + (w * 64 + j * 512) * 16;                \
      __builtin_amdgcn_global_load_lds(                                         \
          (const __attribute__((address_space(1))) void*)src,                   \
          (__attribute__((address_space(3))) void*)dst, 16, 0, 0);              \
    }                                                                           \
  }

#define KSTEP(KS_, BUFO_)                                                       \
  {                                                                             \
    i32x4 afr[4], bfr[2];                                                       \
    _Pragma("unroll")                                                           \
    for (int mf = 0; mf < 4; ++mf)                                              \
      afr[mf] = *(const i32x4*)(lA + (BUFO_) + ((KS_) * 2 + h) * 4096 +         \
                                (wm * 128 + mf * 32 + l31) * 16);               \
    _Pragma("unroll")                                                           \
    for (int nf = 0; nf < 2; ++nf)                                              \
      bfr[nf] = *(const i32x4*)(lB + (BUFO_) + ((KS_) * 2 + h) * 4096 +         \
                                (wn * 64 + nf * 32 + l31) * 16);                \
    __builtin_amdgcn_s_setprio(1);                                              \
    _Pragma("unroll")                                                           \
    for (int mf = 0; mf < 4; ++mf) {                                            \
      acc[mf][0] = __builtin_amdgcn_mfma_i32_32x32x32_i8(afr[mf], bfr[0],       \
                                                         acc[mf][0], 0, 0, 0);  \
      acc[mf][1] = __builtin_amdgcn_mfma_i32_32x32x32_i8(afr[mf], bfr[1],       \
                                                         acc[mf][1], 0, 0, 0);  \
    }                                                                           \
    __builtin_amdgcn_s_setprio(0);                                              \
  }

__global__ __launch_bounds__(NTHR, 1)
void gemm_i8(const signed char* __restrict__ XQ, const signed char* __restrict__ BQ,
             const float* __restrict__ XS, const float* __restrict__ SC,
             float* __restrict__ OUT) {
  __shared__ signed char lA[3 * 16384];   // A: [buf][chunk c][row m][16]
  __shared__ signed char lB[3 * 16384];   // B: [buf][chunk c][col n][16]

  const int tid  = threadIdx.x;
  const int lane = tid & 63;
  const int w    = tid >> 6;     // 0..7
  const int wm   = w >> 2;       // 0..1 (M half)
  const int wn   = w & 3;        // 0..3 (N quarter)
  const int l31  = lane & 31;
  const int h    = lane >> 5;    // half-wave -> k-chunk parity

  // bijective XCD swizzle: 512 blocks = 8 XCD x 64; each XCD owns 2 n-tiles
  const int orig = blockIdx.y * gridDim.x + blockIdx.x;
  const int xcd  = orig & 7;
  const int idx  = orig >> 3;                  // 0..63
  const int m0   = (idx >> 1) * BM;            // 32 m-tiles
  const int n0   = (xcd * 2 + (idx & 1)) * BN; // 16 n-tiles

  i32x16 acc[4][2];
#pragma unroll
  for (int mf = 0; mf < 4; ++mf)
#pragma unroll
    for (int nf = 0; nf < 2; ++nf)
      acc[mf][nf] = (i32x16)(0);

  // rotating buffer byte-offsets: cur (compute), nxt (landing), stg (issue)
  int cur = 0, nxt = 16384, stg = 32768;

  // prologue: tiles 0 and 1 in flight (8 insts); drain tile 0 -> vmcnt(4)
  STAGE_A(cur, 0);
  STAGE_B(cur, 0);
  STAGE_A(nxt, 1);
  STAGE_B(nxt, 1);
  asm volatile("s_waitcnt vmcnt(4)" ::: "memory");
  __builtin_amdgcn_s_barrier();

  for (int kt = 0; kt < NT; ++kt) {
    const bool st = (kt + 2 < NT);
    if (st) {
      STAGE_A(stg, kt + 2);
      STAGE_B(stg, kt + 2);
    }
    KSTEP(0, cur)
    KSTEP(1, cur)
    if (st) {
      asm volatile("s_waitcnt vmcnt(4)" ::: "memory");  // kt+1 resident
    } else {
      asm volatile("s_waitcnt vmcnt(0)" ::: "memory");  // tail drain
    }
    __builtin_amdgcn_s_barrier();
    const int t = cur; cur = nxt; nxt = stg; stg = t;   // rotate
  }

  // ---- epilogue: C/D (32x32): col=lane&31, row=(reg&3)+8*(reg>>2)+4*h ----
  const float sc = SC[0] / 127.f;
#pragma unroll
  for (int mf = 0; mf < 4; ++mf) {
    float fs[16];
#pragma unroll
    for (int r = 0; r < 16; ++r) {
      const int mm = m0 + wm * 128 + mf * 32 + 4 * h + (r & 3) + 8 * (r >> 2);
      fs[r] = sc * XS[mm];
    }
#pragma unroll
    for (int nf = 0; nf < 2; ++nf) {
      const int ncol = n0 + wn * 64 + nf * 32 + l31;
#pragma unroll
      for (int r = 0; r < 16; ++r) {
        const int mm = m0 + wm * 128 + mf * 32 + 4 * h + (r & 3) + 8 * (r >> 2);
        OUT[(size_t)mm * OUT_F + ncol] = (float)acc[mf][nf][r] * fs[r];
      }
    }
  }
}

// ------- pass 2 (fallback, ws-small): verified baseline gemm, inline B -------
__global__ __launch_bounds__(256, 2)
void gemm_i8_pw(const signed char* __restrict__ XQ, const unsigned* __restrict__ PW,
                const float* __restrict__ XS, const float* __restrict__ SC,
                float* __restrict__ OUT) {
  __shared__ signed char lA[256 * 128];

  const int tid  = threadIdx.x;
  const int lane = tid & 63;
  const int w    = tid >> 6;
  const int wm   = w >> 1;
  const int wn   = w & 1;
  const int l31  = lane & 31;
  const int h    = lane >> 5;

  const int m0 = blockIdx.y * 256;
  const int n0 = blockIdx.x * 128;

  i32x16 acc[4][2];
#pragma unroll
  for (int mf = 0; mf < 4; ++mf)
#pragma unroll
    for (int nf = 0; nf < 2; ++nf)
      acc[mf][nf] = (i32x16)(0);

  const unsigned* pb0 = PW + (size_t)(n0 + wn * 64 + 0 * 32 + l31) * PACKED;
  const unsigned* pb1 = PW + (size_t)(n0 + wn * 64 + 1 * 32 + l31) * PACKED;

  for (int kt = 0; kt < IN_F / 128; ++kt) {
#pragma unroll
    for (int cc = 0; cc < 2; ++cc) {
      const int c = w * 2 + cc;
#pragma unroll
      for (int rb = 0; rb < 4; ++rb) {
        const signed char* src =
            XQ + (size_t)(m0 + rb * 64 + lane) * IN_F + kt * 128 + c * 16;
        signed char* dst = lA + c * 4096 + rb * 1024;
        __builtin_amdgcn_global_load_lds(
            (const __attribute__((address_space(1))) void*)src,
            (__attribute__((address_space(3))) void*)dst, 16, 0, 0);
      }
    }

    unsigned bw0[4], bw1[4];
#pragma unroll
    for (int ks = 0; ks < 4; ++ks) {
      bw0[ks] = pb0[kt * 8 + ks * 2 + h];
      bw1[ks] = pb1[kt * 8 + ks * 2 + h];
    }

    __syncthreads();

#pragma unroll
    for (int ks = 0; ks < 4; ++ks) {
      i32x4 bfr0 = unpack16(bw0[ks]);
      i32x4 bfr1 = unpack16(bw1[ks]);
      i32x4 afr[4];
#pragma unroll
      for (int mf = 0; mf < 4; ++mf)
        afr[mf] = *(const i32x4*)(lA + (ks * 2 + h) * 4096 +
                                  (wm * 128 + mf * 32 + l31) * 16);
#pragma unroll
      for (int mf = 0; mf < 4; ++mf) {
        acc[mf][0] = __builtin_amdgcn_mfma_i32_32x32x32_i8(afr[mf], bfr0, acc[mf][0], 0, 0, 0);
        acc[mf][1] = __builtin_amdgcn_mfma_i32_32x32x32_i8(afr[mf], bfr1, acc[mf][1], 0, 0, 0);
      }
    }
    __syncthreads();
  }

  const float sc = SC[0] / 127.f;
#pragma unroll
  for (int mf = 0; mf < 4; ++mf) {
    float fs[16];
#pragma unroll
    for (int r = 0; r < 16; ++r) {
      const int mm = m0 + wm * 128 + mf * 32 + 4 * h + (r & 3) + 8 * (r >> 2);
      fs[r] = sc * XS[mm];
    }
#pragma unroll
    for (int nf = 0; nf < 2; ++nf) {
      const int ncol = n0 + wn * 64 + nf * 32 + l31;
#pragma unroll
      for (int r = 0; r < 16; ++r) {
        const int mm = m0 + wm * 128 + mf * 32 + 4 * h + (r & 3) + 8 * (r >> 2);
        OUT[(size_t)mm * OUT_F + ncol] = (float)acc[mf][nf][r] * fs[r];
      }
    }
  }
}

extern "C" void kernel_launch(void* const* d_in, const int* in_sizes, int n_in,
                              void* d_out, int out_size, void* d_ws, size_t ws_size,
                              hipStream_t stream) {
  const float*    x  = (const float*)d_in[0];
  const unsigned* pw = (const unsigned*)d_in[1];
  const float*    sc = (const float*)d_in[2];
  float*          out = (float*)d_out;

  signed char* xq = (signed char*)d_ws;
  float*       xs = (float*)((char*)d_ws + XQ_BYTES);

  if (ws_size >= WS_NEED) {
    // fast path: fused prep + triple-buffer never-drain gemm
    signed char* bq = (signed char*)d_ws + BQ_OFF;
    prep<<<dim3(TOKENS / 4 + OUT_F * PACKED / 256), dim3(256), 0, stream>>>(
        x, xq, xs, pw, bq);
    dim3 grid(OUT_F / BN, TOKENS / BM);  // (16, 32)
    gemm_i8<<<grid, dim3(NTHR), 0, stream>>>(xq, bq, xs, sc, out);
  } else {
    // fallback: verified baseline gemm, inline ternary unpack (fits 33.6 MB ws)
    prep<<<dim3(TOKENS / 4), dim3(256), 0, stream>>>(x, xq, xs, pw, nullptr);
    dim3 grid(OUT_F / 128, TOKENS / 256);  // (32, 32)
    gemm_i8_pw<<<grid, dim3(256), 0, stream>>>(xq, pw, xs, sc, out);
  }
}